// Round 5
// baseline (437.656 us; speedup 1.0000x reference)
//
#include <hip/hip_runtime.h>

#define N_NODES  500000
#define HIDDEN   256
#define N_GRAPHS 8192
#define NTILES   ((N_NODES + 63) / 64)   // 7813
#define NBLOCKS  512

typedef float f32x4 __attribute__((ext_vector_type(4)));
typedef short s16x8 __attribute__((ext_vector_type(8)));

__device__ __forceinline__ unsigned short f2bf(float f) {
    unsigned int u = __float_as_uint(f);
    u += 0x7fffu + ((u >> 16) & 1u);   // RNE round to bf16
    return (unsigned short)(u >> 16);
}

// Pack W1 [K=256][N=256] fp32 into bf16 B-fragments, grouped per wave-slice.
// slot = (wave*8 + kt)*4 + ntp ; nt = wave*4 + ntp
// w1pack[(slot*64 + lane)*8 + j] = bf16( W1[kt*32 + (lane>>4)*8 + j][nt*16 + (lane&15)] )
__global__ void prep_w1_kernel(const float* __restrict__ W1,
                               unsigned short* __restrict__ w1pack) {
    int tid  = blockIdx.x * 256 + threadIdx.x;   // 0..8191
    int lane = tid & 63;
    int slot = tid >> 6;                         // 0..127
    int wv   = slot >> 5;
    int kt   = (slot >> 2) & 7;
    int ntp  = slot & 3;
    int nt   = wv * 4 + ntp;
    int krow = kt * 32 + ((lane >> 4) & 3) * 8;
    int col  = nt * 16 + (lane & 15);
    unsigned short tmp[8];
#pragma unroll
    for (int j = 0; j < 8; ++j)
        tmp[j] = f2bf(W1[(size_t)(krow + j) * 256 + col]);
    *(uint4*)(w1pack + (size_t)tid * 8) = *(const uint4*)tmp;
}

__device__ __forceinline__ void flush_seg(float* __restrict__ num,
                                          float* __restrict__ den,
                                          int g, int lane, f32x4 v, float d) {
    float* dst = num + (size_t)g * HIDDEN + lane * 4;
    atomicAdd(dst + 0, v[0]);
    atomicAdd(dst + 1, v[1]);
    atomicAdd(dst + 2, v[2]);
    atomicAdd(dst + 3, v[3]);
    if (lane == 0) atomicAdd(den + g, d);
}

// Persistent blocks: 512 blocks x 256 threads (2 blocks/CU), grid-stride tiles.
// Wave w holds B-fragments for cols [64w, 64w+64) in 128 VGPRs.
// LDS: x tile fp32 [64][256] XOR-swizzled (64 KiB) + 1 KiB logit partials.
__launch_bounds__(256, 2)
__global__ void attn_pool_main(const float* __restrict__ x,
                               const int*   __restrict__ batch,
                               const float* __restrict__ b1,
                               const float* __restrict__ W2,
                               const float* __restrict__ b2,
                               const unsigned short* __restrict__ w1pack,
                               float* __restrict__ num,
                               float* __restrict__ den) {
    __shared__ float xlds[64 * 256];   // 64 KiB
    __shared__ float plds[256];        // per-wave logit partials [wave][row]

    const int tid  = threadIdx.x;
    const int wave = tid >> 6;
    const int lane = tid & 63;
    const int cl   = lane & 15;
    const int kgrp = lane >> 4;

    // ---- one-time: B fragments into registers (32 x dwordx4 per lane) ----
    s16x8 bfr[8][4];
#pragma unroll
    for (int kt = 0; kt < 8; ++kt)
#pragma unroll
        for (int ntp = 0; ntp < 4; ++ntp)
            bfr[kt][ntp] = *(const s16x8*)(w1pack +
                ((size_t)(((wave * 8 + kt) * 4 + ntp) * 64 + lane) << 3));

    float b1c[4], w2c[4];
#pragma unroll
    for (int ntp = 0; ntp < 4; ++ntp) {
        int nt = wave * 4 + ntp;
        b1c[ntp] = b1[nt * 16 + cl];
        w2c[ntp] = W2[nt * 16 + cl];
    }
    const float b2v = b2[0];

    for (int t = blockIdx.x; t < NTILES; t += NBLOCKS) {
        const int base = t * 64;

        // ---- stage x tile fp32, swizzle 16B-unit idx ^= (row&7) ----
#pragma unroll
        for (int i = 0; i < 16; ++i) {
            int u   = tid + i * 256;
            int row = u >> 6;
            int c4  = u & 63;
            f32x4 v = {0.f, 0.f, 0.f, 0.f};
            int grow = base + row;
            if (grow < N_NODES)
                v = *(const f32x4*)(x + (size_t)grow * HIDDEN + (size_t)c4 * 4);
            *(f32x4*)(xlds + row * 256 + ((c4 ^ (row & 7)) << 2)) = v;
        }
        const int tileBase = base + wave * 16;
        int bval = 0;
        if (tileBase < N_NODES) bval = batch[tileBase + cl];
        __syncthreads();

        // ---- GEMM: acc[rt][ntp], A from LDS, B from registers ----
        f32x4 acc[4][4];
#pragma unroll
        for (int rt = 0; rt < 4; ++rt)
#pragma unroll
            for (int ntp = 0; ntp < 4; ++ntp)
                acc[rt][ntp] = (f32x4){0.f, 0.f, 0.f, 0.f};

#pragma unroll
        for (int kt = 0; kt < 8; ++kt) {
#pragma unroll
            for (int rt = 0; rt < 4; ++rt) {
                int rowL = rt * 16 + cl;
                int c0u  = kt * 8 + kgrp * 2;
                f32x4 a0 = *(const f32x4*)(xlds + rowL * 256 + (((c0u    ) ^ (rowL & 7)) << 2));
                f32x4 a1 = *(const f32x4*)(xlds + rowL * 256 + (((c0u + 1) ^ (rowL & 7)) << 2));
                s16x8 af;
                af[0] = (short)f2bf(a0[0]); af[1] = (short)f2bf(a0[1]);
                af[2] = (short)f2bf(a0[2]); af[3] = (short)f2bf(a0[3]);
                af[4] = (short)f2bf(a1[0]); af[5] = (short)f2bf(a1[1]);
                af[6] = (short)f2bf(a1[2]); af[7] = (short)f2bf(a1[3]);
#pragma unroll
                for (int ntp = 0; ntp < 4; ++ntp)
                    acc[rt][ntp] = __builtin_amdgcn_mfma_f32_16x16x32_bf16(
                        af, bfr[kt][ntp], acc[rt][ntp], 0, 0, 0);
            }
        }

        // ---- tanh + partial logit over this wave's 64 cols ----
        float sj[4][4];
#pragma unroll
        for (int rt = 0; rt < 4; ++rt)
#pragma unroll
            for (int j = 0; j < 4; ++j) sj[rt][j] = 0.f;
#pragma unroll
        for (int rt = 0; rt < 4; ++rt)
#pragma unroll
            for (int ntp = 0; ntp < 4; ++ntp)
#pragma unroll
                for (int j = 0; j < 4; ++j) {
                    float h = acc[rt][ntp][j] + b1c[ntp];
                    h = fminf(fmaxf(h, -15.f), 15.f);
                    float e2 = __expf(2.f * h);
                    float th = (e2 - 1.f) * __builtin_amdgcn_rcpf(e2 + 1.f);
                    sj[rt][j] += th * w2c[ntp];
                }
        // reduce across 16 lanes of each kgrp group
#pragma unroll
        for (int m = 1; m < 16; m <<= 1)
#pragma unroll
            for (int rt = 0; rt < 4; ++rt)
#pragma unroll
                for (int j = 0; j < 4; ++j)
                    sj[rt][j] += __shfl_xor(sj[rt][j], m, 64);
        if (cl == 0) {
#pragma unroll
            for (int rt = 0; rt < 4; ++rt)
#pragma unroll
                for (int j = 0; j < 4; ++j)
                    plds[wave * 64 + rt * 16 + kgrp * 4 + j] = sj[rt][j];
        }
        __syncthreads();

        // ---- combine 4 waves' partials -> e per row ----
        int rr = wave * 16 + cl;
        float logit = plds[rr] + plds[64 + rr] + plds[128 + rr] + plds[192 + rr] + b2v;
        float el = __expf(logit);

        // ---- weighted segment accumulation (batch sorted) ----
        if (tileBase < N_NODES) {
            f32x4 accv = {0.f, 0.f, 0.f, 0.f};
            float accden = 0.f;
            int gcur = __shfl(bval, 0, 64);
#pragma unroll
            for (int r = 0; r < 16; ++r) {
                int   g  = __shfl(bval, r, 64);
                float er = __shfl(el, r, 64);
                if (g != gcur) {       // wave-uniform branch
                    flush_seg(num, den, gcur, lane, accv, accden);
                    accv = (f32x4){0.f, 0.f, 0.f, 0.f};
                    accden = 0.f;
                    gcur = g;
                }
                int rl = wave * 16 + r;
                f32x4 xv = *(const f32x4*)(xlds + rl * 256 + ((lane ^ (rl & 7)) << 2));
                accv += er * xv;
                accden += er;
            }
            flush_seg(num, den, gcur, lane, accv, accden);
        }
        __syncthreads();   // xlds/plds consumed before next tile's stage
    }
}

__global__ void finalize_kernel(float* __restrict__ out,
                                const float* __restrict__ den) {
    int i = blockIdx.x * 256 + threadIdx.x;      // 0..2M-1
    out[i] = out[i] / (den[i >> 8] + 1e-8f);
}

extern "C" void kernel_launch(void* const* d_in, const int* in_sizes, int n_in,
                              void* d_out, int out_size, void* d_ws, size_t ws_size,
                              hipStream_t stream) {
    const float* x     = (const float*)d_in[0];
    const int*   batch = (const int*)d_in[1];
    const float* W1    = (const float*)d_in[2];
    const float* b1    = (const float*)d_in[3];
    const float* W2    = (const float*)d_in[4];
    const float* b2    = (const float*)d_in[5];
    float* out = (float*)d_out;

    unsigned short* w1pack = (unsigned short*)d_ws;              // 128 KiB
    float* den = (float*)((char*)d_ws + 131072);                 // 32 KiB

    hipMemsetAsync(d_out, 0, (size_t)N_GRAPHS * HIDDEN * sizeof(float), stream);
    hipMemsetAsync(den, 0, (size_t)N_GRAPHS * sizeof(float), stream);

    prep_w1_kernel<<<32, 256, 0, stream>>>(W1, w1pack);

    attn_pool_main<<<NBLOCKS, 256, 0, stream>>>(x, batch, b1, W2, b2, w1pack, out, den);

    finalize_kernel<<<(N_GRAPHS * HIDDEN) / 256, 256, 0, stream>>>(out, den);
}

// Round 6
// 321.092 us; speedup vs baseline: 1.3630x; 1.3630x over previous
//
#include <hip/hip_runtime.h>

#define N_NODES  500000
#define HIDDEN   256
#define N_GRAPHS 8192
#define NTILES   ((N_NODES + 63) / 64)   // 7813

typedef float f32x4 __attribute__((ext_vector_type(4)));
typedef short s16x8 __attribute__((ext_vector_type(8)));

__device__ __forceinline__ unsigned short f2bf(float f) {
    unsigned int u = __float_as_uint(f);
    u += 0x7fffu + ((u >> 16) & 1u);   // RNE round to bf16
    return (unsigned short)(u >> 16);
}

// Pack W1 [K=256][N=256] fp32 into bf16 B-fragments, grouped per wave-slice.
// slot = (wave*8 + kt)*4 + ntp ; nt = wave*4 + ntp
// w1pack[(slot*64 + lane)*8 + j] = bf16( W1[kt*32 + (lane>>4)*8 + j][nt*16 + (lane&15)] )
__global__ void prep_w1_kernel(const float* __restrict__ W1,
                               unsigned short* __restrict__ w1pack) {
    int tid  = blockIdx.x * 256 + threadIdx.x;   // 0..8191
    int lane = tid & 63;
    int slot = tid >> 6;                         // 0..127
    int wv   = slot >> 5;
    int kt   = (slot >> 2) & 7;
    int ntp  = slot & 3;
    int nt   = wv * 4 + ntp;
    int krow = kt * 32 + ((lane >> 4) & 3) * 8;
    int col  = nt * 16 + (lane & 15);
    unsigned short tmp[8];
#pragma unroll
    for (int j = 0; j < 8; ++j)
        tmp[j] = f2bf(W1[(size_t)(krow + j) * 256 + col]);
    *(uint4*)(w1pack + (size_t)tid * 8) = *(const uint4*)tmp;
}

__device__ __forceinline__ void flush_seg(float* __restrict__ num,
                                          float* __restrict__ den,
                                          int g, int lane, f32x4 v, float d) {
    float* dst = num + (size_t)g * HIDDEN + lane * 4;
    atomicAdd(dst + 0, v[0]);
    atomicAdd(dst + 1, v[1]);
    atomicAdd(dst + 2, v[2]);
    atomicAdd(dst + 3, v[3]);
    if (lane == 0) atomicAdd(den + g, d);
}

// One block per 64-node tile, 256 threads = 4 waves.
// LDS: x tile as bf16 [64 rows][32 units of 16B], XOR-swizzled (32 KiB) + 1 KiB partials.
// -> 4 blocks/CU (135 KiB LDS), 4 waves/SIMD. B-fragments stream from L2-hot w1pack.
__launch_bounds__(256, 4)
__global__ void attn_pool_main(const float* __restrict__ x,
                               const int*   __restrict__ batch,
                               const float* __restrict__ b1,
                               const float* __restrict__ W2,
                               const float* __restrict__ b2,
                               const unsigned short* __restrict__ w1pack,
                               float* __restrict__ num,
                               float* __restrict__ den) {
    __shared__ unsigned short xbf[64 * 256];   // 32 KiB, unit-swizzled
    __shared__ float plds[256];                // per-wave logit partials [wave][row]

    const int tid  = threadIdx.x;
    const int wave = tid >> 6;
    const int lane = tid & 63;
    const int cl   = lane & 15;
    const int kgrp = lane >> 4;
    const int base = blockIdx.x * 64;

    // ---- stage x tile -> bf16 LDS; 16B-unit index ^= (row&7) ----
    // unit v = row*32 + cu holds cols [cu*8, cu*8+8) of row as 8 bf16.
#pragma unroll
    for (int i = 0; i < 8; ++i) {
        int v   = tid + i * 256;      // 0..2047
        int row = v >> 5;
        int cu  = v & 31;
        f32x4 a = {0.f, 0.f, 0.f, 0.f}, c = {0.f, 0.f, 0.f, 0.f};
        int grow = base + row;
        if (grow < N_NODES) {
            const float* p = x + (size_t)grow * HIDDEN + cu * 8;
            a = *(const f32x4*)p;
            c = *(const f32x4*)(p + 4);
        }
        s16x8 w;
        w[0] = (short)f2bf(a[0]); w[1] = (short)f2bf(a[1]);
        w[2] = (short)f2bf(a[2]); w[3] = (short)f2bf(a[3]);
        w[4] = (short)f2bf(c[0]); w[5] = (short)f2bf(c[1]);
        w[6] = (short)f2bf(c[2]); w[7] = (short)f2bf(c[3]);
        *(s16x8*)(xbf + (size_t)(row * 32 + (cu ^ (row & 7))) * 8) = w;
    }

    const int tileBase = base + wave * 16;
    int bval = 0;
    if (tileBase < N_NODES) bval = batch[tileBase + cl];

    float b1c[4], w2c[4];
#pragma unroll
    for (int ntp = 0; ntp < 4; ++ntp) {
        int nt = wave * 4 + ntp;
        b1c[ntp] = b1[nt * 16 + cl];
        w2c[ntp] = W2[nt * 16 + cl];
    }
    const float b2v = b2[0];
    __syncthreads();

    // ---- GEMM: A from bf16 LDS, B streamed from L2-hot w1pack ----
    f32x4 acc[4][4];
#pragma unroll
    for (int rt = 0; rt < 4; ++rt)
#pragma unroll
        for (int ntp = 0; ntp < 4; ++ntp)
            acc[rt][ntp] = (f32x4){0.f, 0.f, 0.f, 0.f};

#pragma unroll
    for (int kt = 0; kt < 8; ++kt) {
        s16x8 bf[4];
#pragma unroll
        for (int ntp = 0; ntp < 4; ++ntp)
            bf[ntp] = *(const s16x8*)(w1pack +
                ((size_t)(((wave * 8 + kt) * 4 + ntp) * 64 + lane) << 3));
#pragma unroll
        for (int rt = 0; rt < 4; ++rt) {
            int row = rt * 16 + cl;
            int cu  = kt * 4 + kgrp;
            s16x8 af = *(const s16x8*)(xbf +
                (size_t)(row * 32 + (cu ^ (row & 7))) * 8);
#pragma unroll
            for (int ntp = 0; ntp < 4; ++ntp)
                acc[rt][ntp] = __builtin_amdgcn_mfma_f32_16x16x32_bf16(
                    af, bf[ntp], acc[rt][ntp], 0, 0, 0);
        }
    }

    // ---- tanh + partial logit over this wave's 64 cols ----
    float sj[4][4];
#pragma unroll
    for (int rt = 0; rt < 4; ++rt)
#pragma unroll
        for (int j = 0; j < 4; ++j) sj[rt][j] = 0.f;
#pragma unroll
    for (int rt = 0; rt < 4; ++rt)
#pragma unroll
        for (int ntp = 0; ntp < 4; ++ntp)
#pragma unroll
            for (int j = 0; j < 4; ++j) {
                float h = acc[rt][ntp][j] + b1c[ntp];
                h = fminf(fmaxf(h, -15.f), 15.f);
                float e2 = __expf(2.f * h);
                float th = (e2 - 1.f) * __builtin_amdgcn_rcpf(e2 + 1.f);
                sj[rt][j] += th * w2c[ntp];
            }
    // reduce across 16 lanes of each kgrp group
#pragma unroll
    for (int m = 1; m < 16; m <<= 1)
#pragma unroll
        for (int rt = 0; rt < 4; ++rt)
#pragma unroll
            for (int j = 0; j < 4; ++j)
                sj[rt][j] += __shfl_xor(sj[rt][j], m, 64);
    if (cl == 0) {
#pragma unroll
        for (int rt = 0; rt < 4; ++rt)
#pragma unroll
            for (int j = 0; j < 4; ++j)
                plds[wave * 64 + rt * 16 + kgrp * 4 + j] = sj[rt][j];
    }
    __syncthreads();

    // ---- combine 4 waves' partials -> e per row ----
    int rr = wave * 16 + cl;
    float logit = plds[rr] + plds[64 + rr] + plds[128 + rr] + plds[192 + rr] + b2v;
    float el = __expf(logit);

    // ---- weighted segment accumulation; x re-read fp32 from global (L3-hot) ----
    if (tileBase < N_NODES) {
        f32x4 accv = {0.f, 0.f, 0.f, 0.f};
        float accden = 0.f;
        int gcur = __shfl(bval, 0, 64);
#pragma unroll
        for (int r = 0; r < 16; ++r) {
            int   g  = __shfl(bval, r, 64);
            float er = __shfl(el, r, 64);
            if (g != gcur) {           // wave-uniform branch
                flush_seg(num, den, gcur, lane, accv, accden);
                accv = (f32x4){0.f, 0.f, 0.f, 0.f};
                accden = 0.f;
                gcur = g;
            }
            f32x4 xv = *(const f32x4*)(x + (size_t)(tileBase + r) * HIDDEN + lane * 4);
            accv += er * xv;
            accden += er;
        }
        flush_seg(num, den, gcur, lane, accv, accden);
    }
}

__global__ void finalize_kernel(float* __restrict__ out,
                                const float* __restrict__ den) {
    int i = blockIdx.x * 256 + threadIdx.x;      // 0..2M-1
    out[i] = out[i] / (den[i >> 8] + 1e-8f);
}

extern "C" void kernel_launch(void* const* d_in, const int* in_sizes, int n_in,
                              void* d_out, int out_size, void* d_ws, size_t ws_size,
                              hipStream_t stream) {
    const float* x     = (const float*)d_in[0];
    const int*   batch = (const int*)d_in[1];
    const float* W1    = (const float*)d_in[2];
    const float* b1    = (const float*)d_in[3];
    const float* W2    = (const float*)d_in[4];
    const float* b2    = (const float*)d_in[5];
    float* out = (float*)d_out;

    unsigned short* w1pack = (unsigned short*)d_ws;              // 128 KiB
    float* den = (float*)((char*)d_ws + 131072);                 // 32 KiB

    hipMemsetAsync(d_out, 0, (size_t)N_GRAPHS * HIDDEN * sizeof(float), stream);
    hipMemsetAsync(den, 0, (size_t)N_GRAPHS * sizeof(float), stream);

    prep_w1_kernel<<<32, 256, 0, stream>>>(W1, w1pack);

    attn_pool_main<<<NTILES, 256, 0, stream>>>(x, batch, b1, W2, b2, w1pack, out, den);

    finalize_kernel<<<(N_GRAPHS * HIDDEN) / 256, 256, 0, stream>>>(out, den);
}